// Round 4
// baseline (84.120 us; speedup 1.0000x reference)
//
#include <hip/hip_runtime.h>
#include <hip/hip_cooperative_groups.h>
#include <cmath>

namespace cg = cooperative_groups;

#define HDIM 128
typedef float f32x2 __attribute__((ext_vector_type(2)));

constexpr float EPSF = 1e-5f;
constexpr float K2L  = 2.8853900817779268f;   // 2*log2(e)
constexpr float INVK = 0.34657359027997264f;  // ln(2)/2
constexpr float L2E  = 1.4426950408889634f;   // log2(e)
constexpr float LN2  = 0.6931471805599453f;
constexpr float UXXS = -2.0f * INVK * INVK;   // restores -2*c^2 scale in epilogue

__device__ inline float fast_rcp(float x) { return __builtin_amdgcn_rcpf(x); }

__device__ inline float fast_exp2(float x) {
#if __has_builtin(__builtin_amdgcn_exp2f)
    return __builtin_amdgcn_exp2f(x);
#else
    float r; asm("v_exp_f32 %0, %1" : "=v"(r) : "v"(x)); return r;
#endif
}

__device__ inline float fast_log2(float x) {
#if __has_builtin(__builtin_amdgcn_logf)
    return __builtin_amdgcn_logf(x);
#else
    float r; asm("v_log_f32 %0, %1" : "=v"(r) : "v"(x)); return r;
#endif
}

__device__ inline f32x2 splat2(float v) { return (f32x2){v, v}; }

__device__ inline f32x2 pk_fma(f32x2 a, f32x2 b, f32x2 c) {
#if __has_builtin(__builtin_elementwise_fma)
    return __builtin_elementwise_fma(a, b, c);
#else
    f32x2 r; r.x = fmaf(a.x, b.x, c.x); r.y = fmaf(a.y, b.y, c.y); return r;
#endif
}

__device__ inline double wave_reduce(double v) {
    #pragma unroll
    for (int off = 32; off > 0; off >>= 1)
        v += __shfl_down(v, off, 64);
    return v;
}

// ut,ux carry K2L scale; uxxp = +sum(wd*th*c'^2) carries K2L^2; UXXS restores -2/K2L^2.
__device__ inline void point_epilogue(float u, float ut, float ux, float uxxp,
                                      float x, float tgt,
                                      double& mspe, double& cal, double& bfly)
{
    const float q  = fast_exp2(-fabsf(u) * L2E);           // e^{-|u|}
    const float rp = fast_rcp(1.f + q);
    const float s  = (u >= 0.f) ? rp : q * rp;             // sigmoid(u)
    const float w_log  = fmaxf(u, 0.f) + LN2 * fast_log2(1.f + q);
    const float w_tail = q * fmaf(-0.5f, q, 1.f);          // softplus(u), u << 0
    const float w  = (u < -9.f) ? w_tail : w_log;

    const float utt  = ut * INVK;
    const float uxt  = ux * INVK;
    const float uxxt = uxxp * UXXS;
    const float w_t  = s * utt;
    const float w_x  = s * uxt;
    const float w_xx = fmaf(s * (1.f - s), uxt * uxt, s * uxxt);

    const float pe = (w - tgt) * fast_rcp(tgt + EPSF);
    mspe += (double)pe * (double)pe;

    const float ctm = fmaxf(-w_t, 0.f);
    cal += (double)ctm * (double)ctm;

    const float invw = fast_rcp(w);
    const float a1 = fmaf(-0.5f * x * w_x, invw, 1.f);
    const float g  = fmaf(0.5f, w_xx,
                     fmaf(a1, a1, -0.25f * w_x * (invw + 0.25f)));
    const float btm = fmaxf(-g, 0.f);
    bfly += (double)btm * (double)btm;
}

// Shared body: computes this block's partial sums. Lane pairs split the hidden dim.
__device__ inline void block_body(
    const float* __restrict__ tt, const float* __restrict__ xx,
    const float* __restrict__ tg,
    const float* __restrict__ W1, const float* __restrict__ b1,
    const float* __restrict__ W2, const float* __restrict__ b2,
    int N, float4* cs, double& mspe, double& cal, double& bfly)
{
    const int tid = threadIdx.x;
    for (int i = tid; i < HDIM; i += 256) {
        cs[i] = make_float4(W1[i] * K2L, W1[HDIM + i] * K2L, b1[i] * K2L, W2[i]);
    }
    __syncthreads();
    const float b2v = b2[0];

    const int Ne = N & ~1;
    const f32x2* __restrict__ tt2 = (const f32x2*)tt;
    const f32x2* __restrict__ xx2 = (const f32x2*)xx;
    const f32x2* __restrict__ tg2 = (const f32x2*)tg;

    const int h    = tid & 1;              // hidden-dim half this lane owns
    const int coff = h << 6;               // 0 or 64

    for (int g = blockIdx.x * 256 + tid; g < Ne; g += gridDim.x * 256) {
        const int p = g >> 1;              // pair index (lane pair shares p)
        const f32x2 tv = tt2[p], xv = xx2[p], gv = tg2[p];
        f32x2 u2   = splat2(0.f);
        f32x2 ut2  = splat2(0.f);
        f32x2 ux2  = splat2(0.f);
        f32x2 uxx2 = splat2(0.f);
        #pragma unroll 4
        for (int i = 0; i < HDIM / 2; ++i) {
            const float4 c = cs[i + coff];
            const f32x2 z  = pk_fma(tv, splat2(c.x),
                              pk_fma(xv, splat2(c.y), splat2(c.z)));  // 2z*log2(e)
            f32x2 e;  e.x = fast_exp2(z.x); e.y = fast_exp2(z.y);     // e^{2z}
            const f32x2 ep = e + splat2(1.f);
            f32x2 r;  r.x = fast_rcp(ep.x); r.y = fast_rcp(ep.y);
            const f32x2 th = pk_fma(splat2(-2.f), r, splat2(1.f));    // tanh(z)
            const f32x2 d  = pk_fma(-th, th, splat2(1.f));            // sech^2(z)
            const f32x2 wd = d * splat2(c.w);
            u2   = pk_fma(th, splat2(c.w), u2);
            ut2  = pk_fma(wd, splat2(c.x), ut2);
            ux2  = pk_fma(wd, splat2(c.y), ux2);
            const f32x2 wt  = wd * th;
            const f32x2 wtc = wt * splat2(c.y);
            uxx2 = pk_fma(wtc, splat2(c.y), uxx2);                    // +sum wd*th*c'^2
        }
        u2.x   += __shfl_xor(u2.x,   1, 64);  u2.y   += __shfl_xor(u2.y,   1, 64);
        ut2.x  += __shfl_xor(ut2.x,  1, 64);  ut2.y  += __shfl_xor(ut2.y,  1, 64);
        ux2.x  += __shfl_xor(ux2.x,  1, 64);  ux2.y  += __shfl_xor(ux2.y,  1, 64);
        uxx2.x += __shfl_xor(uxx2.x, 1, 64);  uxx2.y += __shfl_xor(uxx2.y, 1, 64);
        const float u    = (h ? u2.y   : u2.x) + b2v;
        const float ut   =  h ? ut2.y  : ut2.x;
        const float ux   =  h ? ux2.y  : ux2.x;
        const float uxxp =  h ? uxx2.y : uxx2.x;
        const float xs   =  h ? xv.y   : xv.x;
        const float tgs  =  h ? gv.y   : gv.x;
        point_epilogue(u, ut, ux, uxxp, xs, tgs, mspe, cal, bfly);
    }

    if ((N & 1) && blockIdx.x == 0 && tid == 0) {
        const int idx = N - 1;
        const float t = tt[idx], x = xx[idx], tgt = tg[idx];
        float u = 0.f, ut = 0.f, ux = 0.f, uxx = 0.f;
        for (int i = 0; i < HDIM; ++i) {
            const float4 c = cs[i];
            const float zp = fmaf(t, c.x, fmaf(x, c.y, c.z));
            const float e  = fast_exp2(zp);
            const float r  = fast_rcp(e + 1.f);
            const float th = fmaf(-2.f, r, 1.f);
            const float d  = fmaf(-th, th, 1.f);
            const float wd = c.w * d;
            u   = fmaf(c.w, th, u);
            ut  = fmaf(wd, c.x, ut);
            ux  = fmaf(wd, c.y, ux);
            uxx = fmaf(wd * th * c.y, c.y, uxx);
        }
        point_epilogue(u + b2v, ut, ux, uxx, x, tgt, mspe, cal, bfly);
    }
}

__device__ inline void block_reduce_store(double mspe, double cal, double bfly,
                                          double (*sred)[4], double* __restrict__ partials)
{
    const int tid = threadIdx.x;
    double v0 = wave_reduce(mspe), v1 = wave_reduce(cal), v2 = wave_reduce(bfly);
    const int wid = tid >> 6, lane = tid & 63;
    if (lane == 0) { sred[0][wid] = v0; sred[1][wid] = v1; sred[2][wid] = v2; }
    __syncthreads();
    if (tid == 0) {
        double a = 0, b = 0, c = 0;
        #pragma unroll
        for (int wv = 0; wv < 4; ++wv) { a += sred[0][wv]; b += sred[1][wv]; c += sred[2][wv]; }
        partials[blockIdx.x * 3 + 0] = a;
        partials[blockIdx.x * 3 + 1] = b;
        partials[blockIdx.x * 3 + 2] = c;
    }
}

// Cooperative single-dispatch kernel: body -> grid.sync -> block 0 reduces.
__global__ __launch_bounds__(256, 4) void surf_loss_coop(
    const float* __restrict__ tt, const float* __restrict__ xx,
    const float* __restrict__ tg,
    const float* __restrict__ W1, const float* __restrict__ b1,
    const float* __restrict__ W2, const float* __restrict__ b2,
    double* __restrict__ partials, float* __restrict__ out, int N)
{
    __shared__ float4 cs[HDIM];
    __shared__ double sred[3][4];
    double mspe = 0.0, cal = 0.0, bfly = 0.0;
    block_body(tt, xx, tg, W1, b1, W2, b2, N, cs, mspe, cal, bfly);
    block_reduce_store(mspe, cal, bfly, sred, partials);

    cg::this_grid().sync();

    if (blockIdx.x == 0) {
        const int tid = threadIdx.x;
        double a = 0, b = 0, c = 0;
        const int nb = (int)gridDim.x;
        for (int i = tid; i < nb; i += 256) {
            a += partials[i * 3 + 0];
            b += partials[i * 3 + 1];
            c += partials[i * 3 + 2];
        }
        a = wave_reduce(a); b = wave_reduce(b); c = wave_reduce(c);
        const int wid = tid >> 6, lane = tid & 63;
        __syncthreads();   // reuse sred safely
        if (lane == 0) { sred[0][wid] = a; sred[1][wid] = b; sred[2][wid] = c; }
        __syncthreads();
        if (tid == 0) {
            const double inv = 1.0 / (double)N;
            double s0 = 0, s1 = 0, s2 = 0;
            #pragma unroll
            for (int wv = 0; wv < 4; ++wv) { s0 += sred[0][wv]; s1 += sred[1][wv]; s2 += sred[2][wv]; }
            out[0] = (float)(s0 * inv);
            out[1] = (float)(s1 * inv);
            out[2] = (float)(s2 * inv);
        }
    }
}

// Fallback two-kernel path (proven R1/R2 structure).
__global__ __launch_bounds__(256, 4) void surf_loss_main(
    const float* __restrict__ tt, const float* __restrict__ xx,
    const float* __restrict__ tg,
    const float* __restrict__ W1, const float* __restrict__ b1,
    const float* __restrict__ W2, const float* __restrict__ b2,
    double* __restrict__ partials, int N)
{
    __shared__ float4 cs[HDIM];
    __shared__ double sred[3][4];
    double mspe = 0.0, cal = 0.0, bfly = 0.0;
    block_body(tt, xx, tg, W1, b1, W2, b2, N, cs, mspe, cal, bfly);
    block_reduce_store(mspe, cal, bfly, sred, partials);
}

__global__ __launch_bounds__(256) void surf_loss_final(
    const double* __restrict__ partials, int nblocks, float* __restrict__ out, int N)
{
    const int tid = threadIdx.x;
    double a = 0, b = 0, c = 0;
    for (int i = tid; i < nblocks; i += 256) {
        a += partials[i * 3 + 0];
        b += partials[i * 3 + 1];
        c += partials[i * 3 + 2];
    }
    a = wave_reduce(a); b = wave_reduce(b); c = wave_reduce(c);
    __shared__ double sred[3][4];
    const int wid = tid >> 6, lane = tid & 63;
    if (lane == 0) { sred[0][wid] = a; sred[1][wid] = b; sred[2][wid] = c; }
    __syncthreads();
    if (tid == 0) {
        const double inv = 1.0 / (double)N;
        double s0 = 0, s1 = 0, s2 = 0;
        #pragma unroll
        for (int wv = 0; wv < 4; ++wv) { s0 += sred[0][wv]; s1 += sred[1][wv]; s2 += sred[2][wv]; }
        out[0] = (float)(s0 * inv);
        out[1] = (float)(s1 * inv);
        out[2] = (float)(s2 * inv);
    }
}

extern "C" void kernel_launch(void* const* d_in, const int* in_sizes, int n_in,
                              void* d_out, int out_size, void* d_ws, size_t ws_size,
                              hipStream_t stream) {
    const float* tt = (const float*)d_in[0];
    const float* xx = (const float*)d_in[1];
    const float* tg = (const float*)d_in[2];
    const float* W1 = (const float*)d_in[3];
    const float* b1 = (const float*)d_in[4];
    const float* W2 = (const float*)d_in[5];
    const float* b2 = (const float*)d_in[6];
    const int N = in_sizes[0];
    float* outp = (float*)d_out;
    double* partials = (double*)d_ws;

    // One-time capture-safe host queries (no stream ops, no allocs).
    static int g_coop = -1;
    static int g_maxblocks = 0;
    if (g_coop < 0) {
        int dev = 0; hipGetDevice(&dev);
        int attr = 0;
        hipDeviceGetAttribute(&attr, hipDeviceAttributeCooperativeLaunch, dev);
        int ncu = 0;
        hipDeviceGetAttribute(&ncu, hipDeviceAttributeMultiprocessorCount, dev);
        int occ = 0;
        hipOccupancyMaxActiveBlocksPerMultiprocessor(&occ, (const void*)surf_loss_coop, 256, 0);
        g_maxblocks = (occ > 0 && ncu > 0) ? occ * ncu : 0;
        g_coop = (attr != 0 && g_maxblocks > 0) ? 1 : 0;
    }

    int blocks = (N + 255) / 256;
    if (blocks < 1) blocks = 1;
    if (blocks > 1024) blocks = 1024;
    while ((size_t)blocks * 3 * sizeof(double) > ws_size && blocks > 1) blocks >>= 1;

    if (g_coop) {
        int cblocks = blocks;
        if (cblocks > g_maxblocks) cblocks = g_maxblocks;
        void* args[] = { (void*)&tt, (void*)&xx, (void*)&tg, (void*)&W1, (void*)&b1,
                         (void*)&W2, (void*)&b2, (void*)&partials, (void*)&outp, (void*)&N };
        hipError_t e = hipLaunchCooperativeKernel((const void*)surf_loss_coop,
                                                  dim3(cblocks), dim3(256), args, 0, stream);
        if (e == hipSuccess) return;
        (void)hipGetLastError();   // clear and fall through to fallback
        g_coop = 0;
    }

    surf_loss_main<<<blocks, 256, 0, stream>>>(tt, xx, tg, W1, b1, W2, b2, partials, N);
    surf_loss_final<<<1, 256, 0, stream>>>(partials, blocks, outp, N);
}

// Round 5
// 21.340 us; speedup vs baseline: 3.9420x; 3.9420x over previous
//
#include <hip/hip_runtime.h>
#include <cmath>

#define HDIM 128
typedef float f32x2 __attribute__((ext_vector_type(2)));

constexpr float EPSF = 1e-5f;
constexpr float K2L  = 2.8853900817779268f;   // 2*log2(e)
constexpr float INVK = 0.34657359027997264f;  // ln(2)/2
constexpr float L2E  = 1.4426950408889634f;   // log2(e)
constexpr float LN2  = 0.6931471805599453f;
constexpr float UXXS = -2.0f * INVK * INVK;   // restores -2*c^2 scale in epilogue

__device__ inline float fast_rcp(float x) { return __builtin_amdgcn_rcpf(x); }

__device__ inline float fast_exp2(float x) {
#if __has_builtin(__builtin_amdgcn_exp2f)
    return __builtin_amdgcn_exp2f(x);
#else
    float r; asm("v_exp_f32 %0, %1" : "=v"(r) : "v"(x)); return r;
#endif
}

__device__ inline float fast_log2(float x) {
#if __has_builtin(__builtin_amdgcn_logf)
    return __builtin_amdgcn_logf(x);
#else
    float r; asm("v_log_f32 %0, %1" : "=v"(r) : "v"(x)); return r;
#endif
}

__device__ inline f32x2 splat2(float v) { return (f32x2){v, v}; }

__device__ inline f32x2 pk_fma(f32x2 a, f32x2 b, f32x2 c) {
#if __has_builtin(__builtin_elementwise_fma)
    return __builtin_elementwise_fma(a, b, c);
#else
    f32x2 r; r.x = fmaf(a.x, b.x, c.x); r.y = fmaf(a.y, b.y, c.y); return r;
#endif
}

__device__ inline double wave_reduce(double v) {
    #pragma unroll
    for (int off = 32; off > 0; off >>= 1)
        v += __shfl_down(v, off, 64);
    return v;
}

// ut,ux carry K2L scale; uxxp = +sum(wd*th*c'^2) carries K2L^2; UXXS restores -2/K2L^2.
__device__ inline void point_epilogue(float u, float ut, float ux, float uxxp,
                                      float x, float tgt,
                                      double& mspe, double& cal, double& bfly)
{
    const float q  = fast_exp2(-fabsf(u) * L2E);           // e^{-|u|}
    const float rp = fast_rcp(1.f + q);
    const float s  = (u >= 0.f) ? rp : q * rp;             // sigmoid(u)
    const float w_log  = fmaxf(u, 0.f) + LN2 * fast_log2(1.f + q);
    const float w_tail = q * fmaf(-0.5f, q, 1.f);          // softplus(u), u << 0
    const float w  = (u < -9.f) ? w_tail : w_log;

    const float utt  = ut * INVK;
    const float uxt  = ux * INVK;
    const float uxxt = uxxp * UXXS;
    const float w_t  = s * utt;
    const float w_x  = s * uxt;
    const float w_xx = fmaf(s * (1.f - s), uxt * uxt, s * uxxt);

    const float pe = (w - tgt) * fast_rcp(tgt + EPSF);
    mspe += (double)pe * (double)pe;

    const float ctm = fmaxf(-w_t, 0.f);
    cal += (double)ctm * (double)ctm;

    const float invw = fast_rcp(w);
    const float a1 = fmaf(-0.5f * x * w_x, invw, 1.f);
    const float g  = fmaf(0.5f, w_xx,
                     fmaf(a1, a1, -0.25f * w_x * (invw + 0.25f)));
    const float btm = fmaxf(-g, 0.f);
    bfly += (double)btm * (double)btm;
}

// Lane pairs split the hidden dim; odd-lane half stored at cs[65..128] so the
// two wave addresses are 1040 B apart (bank +4) -> no ds_read_b128 conflicts.
__global__ __launch_bounds__(256, 4) void surf_loss_main(
    const float* __restrict__ tt, const float* __restrict__ xx,
    const float* __restrict__ tg,
    const float* __restrict__ W1, const float* __restrict__ b1,
    const float* __restrict__ W2, const float* __restrict__ b2,
    double* __restrict__ partials, int N)
{
    __shared__ float4 cs[130];    // [0..63] = units 0..63, [65..128] = units 64..127
    __shared__ double sred[3][4];
    const int tid = threadIdx.x;
    for (int u = tid; u < HDIM; u += 256) {
        const int slot = u + (u >= 64 ? 1 : 0);
        cs[slot] = make_float4(W1[u] * K2L, W1[HDIM + u] * K2L, b1[u] * K2L, W2[u]);
    }
    __syncthreads();
    const float b2v = b2[0];

    double mspe = 0.0, cal = 0.0, bfly = 0.0;

    const int Ne = N & ~1;
    const f32x2* __restrict__ tt2 = (const f32x2*)tt;
    const f32x2* __restrict__ xx2 = (const f32x2*)xx;
    const f32x2* __restrict__ tg2 = (const f32x2*)tg;

    const int h    = tid & 1;              // hidden-dim half this lane owns
    const int base = h ? 65 : 0;           // padded LDS offset of that half

    for (int g = blockIdx.x * 256 + tid; g < Ne; g += gridDim.x * 256) {
        const int p = g >> 1;              // pair index (lane pair shares p)
        const f32x2 tv = tt2[p], xv = xx2[p], gv = tg2[p];
        f32x2 u2   = splat2(0.f);
        f32x2 ut2  = splat2(0.f);
        f32x2 ux2  = splat2(0.f);
        f32x2 uxx2 = splat2(0.f);
        #pragma unroll 8
        for (int i = 0; i < HDIM / 2; ++i) {
            const float4 c = cs[base + i];
            const f32x2 z  = pk_fma(tv, splat2(c.x),
                              pk_fma(xv, splat2(c.y), splat2(c.z)));  // 2z*log2(e)
            f32x2 e;  e.x = fast_exp2(z.x); e.y = fast_exp2(z.y);     // e^{2z}
            const f32x2 ep = e + splat2(1.f);
            f32x2 r;  r.x = fast_rcp(ep.x); r.y = fast_rcp(ep.y);
            const f32x2 th = pk_fma(splat2(-2.f), r, splat2(1.f));    // tanh(z)
            const f32x2 d  = pk_fma(-th, th, splat2(1.f));            // sech^2(z)
            const f32x2 wd = d * splat2(c.w);
            u2   = pk_fma(th, splat2(c.w), u2);
            ut2  = pk_fma(wd, splat2(c.x), ut2);
            ux2  = pk_fma(wd, splat2(c.y), ux2);
            const f32x2 wt  = wd * th;
            const f32x2 wtc = wt * splat2(c.y);
            uxx2 = pk_fma(wtc, splat2(c.y), uxx2);                    // +sum wd*th*c'^2
        }
        // combine hidden-dim halves with the partner lane (lane^1)
        u2.x   += __shfl_xor(u2.x,   1, 64);  u2.y   += __shfl_xor(u2.y,   1, 64);
        ut2.x  += __shfl_xor(ut2.x,  1, 64);  ut2.y  += __shfl_xor(ut2.y,  1, 64);
        ux2.x  += __shfl_xor(ux2.x,  1, 64);  ux2.y  += __shfl_xor(ux2.y,  1, 64);
        uxx2.x += __shfl_xor(uxx2.x, 1, 64);  uxx2.y += __shfl_xor(uxx2.y, 1, 64);
        // even lane finishes point 2p (.x), odd lane point 2p+1 (.y)
        const float u    = (h ? u2.y   : u2.x) + b2v;
        const float ut   =  h ? ut2.y  : ut2.x;
        const float ux   =  h ? ux2.y  : ux2.x;
        const float uxxp =  h ? uxx2.y : uxx2.x;
        const float xs   =  h ? xv.y   : xv.x;
        const float tgs  =  h ? gv.y   : gv.x;
        point_epilogue(u, ut, ux, uxxp, xs, tgs, mspe, cal, bfly);
    }

    // odd-N tail: one scalar point
    if ((N & 1) && blockIdx.x == 0 && tid == 0) {
        const int idx = N - 1;
        const float t = tt[idx], x = xx[idx], tgt = tg[idx];
        float u = 0.f, ut = 0.f, ux = 0.f, uxx = 0.f;
        for (int i = 0; i < HDIM; ++i) {
            const float4 c = cs[i + (i >= 64 ? 1 : 0)];
            const float zp = fmaf(t, c.x, fmaf(x, c.y, c.z));
            const float e  = fast_exp2(zp);
            const float r  = fast_rcp(e + 1.f);
            const float th = fmaf(-2.f, r, 1.f);
            const float d  = fmaf(-th, th, 1.f);
            const float wd = c.w * d;
            u   = fmaf(c.w, th, u);
            ut  = fmaf(wd, c.x, ut);
            ux  = fmaf(wd, c.y, ux);
            uxx = fmaf(wd * th * c.y, c.y, uxx);
        }
        point_epilogue(u + b2v, ut, ux, uxx, x, tgt, mspe, cal, bfly);
    }

    double v0 = wave_reduce(mspe), v1 = wave_reduce(cal), v2 = wave_reduce(bfly);
    const int wid = tid >> 6, lane = tid & 63;
    if (lane == 0) { sred[0][wid] = v0; sred[1][wid] = v1; sred[2][wid] = v2; }
    __syncthreads();
    if (tid == 0) {
        double a = 0, b = 0, c = 0;
        #pragma unroll
        for (int wv = 0; wv < 4; ++wv) { a += sred[0][wv]; b += sred[1][wv]; c += sred[2][wv]; }
        partials[blockIdx.x * 3 + 0] = a;
        partials[blockIdx.x * 3 + 1] = b;
        partials[blockIdx.x * 3 + 2] = c;
    }
}

__global__ __launch_bounds__(256) void surf_loss_final(
    const double* __restrict__ partials, int nblocks, float* __restrict__ out, int N)
{
    const int tid = threadIdx.x;
    double a = 0, b = 0, c = 0;
    for (int i = tid; i < nblocks; i += 256) {
        a += partials[i * 3 + 0];
        b += partials[i * 3 + 1];
        c += partials[i * 3 + 2];
    }
    a = wave_reduce(a); b = wave_reduce(b); c = wave_reduce(c);
    __shared__ double sred[3][4];
    const int wid = tid >> 6, lane = tid & 63;
    if (lane == 0) { sred[0][wid] = a; sred[1][wid] = b; sred[2][wid] = c; }
    __syncthreads();
    if (tid == 0) {
        const double inv = 1.0 / (double)N;
        double s0 = 0, s1 = 0, s2 = 0;
        #pragma unroll
        for (int wv = 0; wv < 4; ++wv) { s0 += sred[0][wv]; s1 += sred[1][wv]; s2 += sred[2][wv]; }
        out[0] = (float)(s0 * inv);
        out[1] = (float)(s1 * inv);
        out[2] = (float)(s2 * inv);
    }
}

extern "C" void kernel_launch(void* const* d_in, const int* in_sizes, int n_in,
                              void* d_out, int out_size, void* d_ws, size_t ws_size,
                              hipStream_t stream) {
    const float* tt = (const float*)d_in[0];
    const float* xx = (const float*)d_in[1];
    const float* tg = (const float*)d_in[2];
    const float* W1 = (const float*)d_in[3];
    const float* b1 = (const float*)d_in[4];
    const float* W2 = (const float*)d_in[5];
    const float* b2 = (const float*)d_in[6];
    const int N = in_sizes[0];

    int blocks = (N + 255) / 256;           // one thread per point (lane pairs split H)
    if (blocks < 1) blocks = 1;
    if (blocks > 1024) blocks = 1024;
    while ((size_t)blocks * 3 * sizeof(double) > ws_size && blocks > 1) blocks >>= 1;

    double* partials = (double*)d_ws;
    surf_loss_main<<<blocks, 256, 0, stream>>>(tt, xx, tg, W1, b1, W2, b2, partials, N);
    surf_loss_final<<<1, 256, 0, stream>>>(partials, blocks, (float*)d_out, N);
}